// Round 1
// baseline (452.643 us; speedup 1.0000x reference)
//
#include <hip/hip_runtime.h>

#define NCAM 6
#define CCH  128
#define IH   64
#define IW   176
#define NQ   640000           // 200*200*16
#define PIX  (IH * IW)        // 11264 = 352*32

// ---------------------------------------------------------------------------
// Kernel 1: transpose img_feats (cam, c, y, x) -> (cam, y, x, c) so that the
// per-query channel gather is a contiguous 512B read. Classic 32x32 LDS tile.
// PIX = 352*32 and CCH = 4*32 exactly, so no bounds checks.
// ---------------------------------------------------------------------------
__global__ __launch_bounds__(256) void transpose_kernel(
    const float* __restrict__ in, float* __restrict__ out) {
    __shared__ float tile[32][33];           // +1 pad: no bank conflicts
    const int cam   = blockIdx.z;
    const int pbase = blockIdx.x * 32;       // pixel index  (y*W+x)
    const int cbase = blockIdx.y * 32;       // channel index
    const int tx = threadIdx.x, ty = threadIdx.y;

    const float* src = in  + (size_t)cam * CCH * PIX;
    float*       dst = out + (size_t)cam * PIX * CCH;

    #pragma unroll
    for (int j = 0; j < 4; ++j) {
        int c = cbase + ty + j * 8;
        tile[ty + j * 8][tx] = src[(size_t)c * PIX + (pbase + tx)];  // coalesced in p
    }
    __syncthreads();
    #pragma unroll
    for (int j = 0; j < 4; ++j) {
        int p = pbase + ty + j * 8;
        dst[(size_t)p * CCH + (cbase + tx)] = tile[tx][ty + j * 8];  // coalesced in c
    }
}

// ---------------------------------------------------------------------------
// Kernel 2: one thread per query. Resolve highest valid cam, RNE-round the
// projection, gather 128 channels via float4 from the transposed layout,
// scatter to out[c*NQ + q] (coalesced across lanes for every c).
// Branchless invalid handling: cam=max(sel,0), multiply by 0.
// ---------------------------------------------------------------------------
__global__ __launch_bounds__(256) void gather_kernel(
    const float* __restrict__ imgT,     // (cam, y, x, c)
    const float* __restrict__ points,   // (cam, NQ, 2)
    const int*   __restrict__ valid,    // (cam, NQ) int32
    float*       __restrict__ out) {    // (c, NQ)
    const int q = blockIdx.x * 256 + threadIdx.x;

    int sel = -1;
    #pragma unroll
    for (int cam = 0; cam < NCAM; ++cam)
        if (valid[(size_t)cam * NQ + q] != 0) sel = cam;   // keeps highest valid

    const float scale = (sel >= 0) ? 1.0f : 0.0f;
    const int cam = (sel >= 0) ? sel : 0;

    const float2 pt = ((const float2*)points)[(size_t)cam * NQ + q];
    const int x = __float2int_rn(pt.x);   // round-half-to-even, matches jnp.round
    const int y = __float2int_rn(pt.y);

    const float4* src =
        (const float4*)(imgT + (((size_t)cam * IH + y) * IW + x) * CCH);

    #pragma unroll 8
    for (int c4 = 0; c4 < CCH / 4; ++c4) {
        float4 v = src[c4];
        out[(size_t)(c4 * 4 + 0) * NQ + q] = v.x * scale;
        out[(size_t)(c4 * 4 + 1) * NQ + q] = v.y * scale;
        out[(size_t)(c4 * 4 + 2) * NQ + q] = v.z * scale;
        out[(size_t)(c4 * 4 + 3) * NQ + q] = v.w * scale;
    }
}

// ---------------------------------------------------------------------------
// Fallback: gather straight from (cam, c, y, x) if workspace is too small.
// ---------------------------------------------------------------------------
__global__ __launch_bounds__(256) void gather_direct_kernel(
    const float* __restrict__ img,
    const float* __restrict__ points,
    const int*   __restrict__ valid,
    float*       __restrict__ out) {
    const int q = blockIdx.x * 256 + threadIdx.x;

    int sel = -1;
    #pragma unroll
    for (int cam = 0; cam < NCAM; ++cam)
        if (valid[(size_t)cam * NQ + q] != 0) sel = cam;

    const float scale = (sel >= 0) ? 1.0f : 0.0f;
    const int cam = (sel >= 0) ? sel : 0;

    const float2 pt = ((const float2*)points)[(size_t)cam * NQ + q];
    const int x = __float2int_rn(pt.x);
    const int y = __float2int_rn(pt.y);

    const float* src = img + ((size_t)cam * CCH * IH + y) * IW + x;
    #pragma unroll 8
    for (int c = 0; c < CCH; ++c)
        out[(size_t)c * NQ + q] = src[(size_t)c * PIX] * scale;
}

extern "C" void kernel_launch(void* const* d_in, const int* in_sizes, int n_in,
                              void* d_out, int out_size, void* d_ws, size_t ws_size,
                              hipStream_t stream) {
    const float* img    = (const float*)d_in[0];
    const float* points = (const float*)d_in[1];
    const int*   valid  = (const int*)  d_in[2];
    float*       out    = (float*)d_out;

    const size_t need = (size_t)NCAM * CCH * IH * IW * sizeof(float);
    if (ws_size >= need) {
        float* imgT = (float*)d_ws;
        dim3 tb(32, 8, 1);
        dim3 tg(PIX / 32, CCH / 32, NCAM);     // 352 x 4 x 6
        transpose_kernel<<<tg, tb, 0, stream>>>(img, imgT);
        gather_kernel<<<NQ / 256, 256, 0, stream>>>(imgT, points, valid, out);
    } else {
        gather_direct_kernel<<<NQ / 256, 256, 0, stream>>>(img, points, valid, out);
    }
}

// Round 2
// 432.505 us; speedup vs baseline: 1.0466x; 1.0466x over previous
//
#include <hip/hip_runtime.h>

#define NCAM 6
#define CCH  128
#define IH   64
#define IW   176
#define NQ   640000           // 200*200*16
#define PIX  (IH * IW)        // 11264 = 352*32
#define QT   64               // queries per block
#define LSTRIDE 129           // odd LDS stride: phase-C q-major reads are 2-way (free)

// ---------------------------------------------------------------------------
// Kernel 1: transpose img_feats (cam, c, y, x) -> (cam, y, x, c). Unchanged
// from R1 (~15 us, not the bottleneck).
// ---------------------------------------------------------------------------
__global__ __launch_bounds__(256) void transpose_kernel(
    const float* __restrict__ in, float* __restrict__ out) {
    __shared__ float tile[32][33];
    const int cam   = blockIdx.z;
    const int pbase = blockIdx.x * 32;
    const int cbase = blockIdx.y * 32;
    const int tx = threadIdx.x, ty = threadIdx.y;

    const float* src = in  + (size_t)cam * CCH * PIX;
    float*       dst = out + (size_t)cam * PIX * CCH;

    #pragma unroll
    for (int j = 0; j < 4; ++j) {
        int c = cbase + ty + j * 8;
        tile[ty + j * 8][tx] = src[(size_t)c * PIX + (pbase + tx)];
    }
    __syncthreads();
    #pragma unroll
    for (int j = 0; j < 4; ++j) {
        int p = pbase + ty + j * 8;
        dst[(size_t)p * CCH + (cbase + tx)] = tile[tx][ty + j * 8];
    }
}

// ---------------------------------------------------------------------------
// Kernel 2: LDS-staged gather. Block = 256 threads, QT=64 queries.
//  A) threads 0..63 resolve cam/scale/base-offset for one query each.
//  B) 8 groups of 32 lanes: each group reads one query's 512B feature vector
//     as ONE coalesced 32-lane global_load_dwordx4 (each 64B line fetched
//     once, fully used) -> LDS, scale applied.
//  C) lanes over q: float4 stores to out (c, q), LDS reads 2-way conflict
//     (free at stride 129).
// LDS: 64*129*4 + 64*8 = 33.5 KB -> 4 blocks/CU, 16 waves/CU.
// ---------------------------------------------------------------------------
__global__ __launch_bounds__(256) void gather_lds_kernel(
    const float* __restrict__ imgT,     // (cam, y, x, c)
    const float* __restrict__ points,   // (cam, NQ, 2)
    const int*   __restrict__ valid,    // (cam, NQ) int32
    float*       __restrict__ out) {    // (c, NQ)
    __shared__ float feat[QT * LSTRIDE];
    __shared__ int   sbase[QT];
    __shared__ float sscale[QT];

    const int t     = threadIdx.x;
    const int qbase = blockIdx.x * QT;

    // ---- Phase A: resolve ----
    if (t < QT) {
        const int q = qbase + t;
        int sel = -1;
        #pragma unroll
        for (int cam = 0; cam < NCAM; ++cam)
            if (valid[(size_t)cam * NQ + q] != 0) sel = cam;   // highest valid
        const int cam = (sel >= 0) ? sel : 0;
        sscale[t] = (sel >= 0) ? 1.0f : 0.0f;
        const float2 pt = ((const float2*)points)[(size_t)cam * NQ + q];
        const int x = __float2int_rn(pt.x);   // RNE == jnp.round
        const int y = __float2int_rn(pt.y);
        sbase[t] = ((cam * IH + y) * IW + x) * CCH;   // word offset, < 2^31
    }
    __syncthreads();

    // ---- Phase B: coalesced 512B reads -> LDS ----
    {
        const int grp  = t >> 5;      // 0..7
        const int lane = t & 31;
        #pragma unroll
        for (int i = 0; i < 8; ++i) {
            const int ql = i * 8 + grp;
            const float s = sscale[ql];
            const float4 v = *((const float4*)(imgT + sbase[ql]) + lane);
            const int w = ql * LSTRIDE + 4 * lane;
            feat[w + 0] = v.x * s;
            feat[w + 1] = v.y * s;
            feat[w + 2] = v.z * s;
            feat[w + 3] = v.w * s;
        }
    }
    __syncthreads();

    // ---- Phase C: LDS -> out, float4 stores, lanes over q ----
    {
        const int l    = t & 63;
        const int wv   = t >> 6;      // wave id 0..3
        const int qq   = l & 15;      // q-quad 0..15
        const int csub = l >> 4;      // 0..3
        #pragma unroll
        for (int iter = 0; iter < 8; ++iter) {
            const int c    = iter * 16 + wv * 4 + csub;
            const int qoff = 4 * qq;
            float4 v;
            v.x = feat[(qoff + 0) * LSTRIDE + c];
            v.y = feat[(qoff + 1) * LSTRIDE + c];
            v.z = feat[(qoff + 2) * LSTRIDE + c];
            v.w = feat[(qoff + 3) * LSTRIDE + c];
            *(float4*)(out + (size_t)c * NQ + qbase + qoff) = v;
        }
    }
}

// ---------------------------------------------------------------------------
// Fallback: direct gather from (cam, c, y, x) if workspace too small.
// ---------------------------------------------------------------------------
__global__ __launch_bounds__(256) void gather_direct_kernel(
    const float* __restrict__ img,
    const float* __restrict__ points,
    const int*   __restrict__ valid,
    float*       __restrict__ out) {
    const int q = blockIdx.x * 256 + threadIdx.x;

    int sel = -1;
    #pragma unroll
    for (int cam = 0; cam < NCAM; ++cam)
        if (valid[(size_t)cam * NQ + q] != 0) sel = cam;

    const float scale = (sel >= 0) ? 1.0f : 0.0f;
    const int cam = (sel >= 0) ? sel : 0;

    const float2 pt = ((const float2*)points)[(size_t)cam * NQ + q];
    const int x = __float2int_rn(pt.x);
    const int y = __float2int_rn(pt.y);

    const float* src = img + ((size_t)cam * CCH * IH + y) * IW + x;
    #pragma unroll 8
    for (int c = 0; c < CCH; ++c)
        out[(size_t)c * NQ + q] = src[(size_t)c * PIX] * scale;
}

extern "C" void kernel_launch(void* const* d_in, const int* in_sizes, int n_in,
                              void* d_out, int out_size, void* d_ws, size_t ws_size,
                              hipStream_t stream) {
    const float* img    = (const float*)d_in[0];
    const float* points = (const float*)d_in[1];
    const int*   valid  = (const int*)  d_in[2];
    float*       out    = (float*)d_out;

    const size_t need = (size_t)NCAM * CCH * IH * IW * sizeof(float);
    if (ws_size >= need) {
        float* imgT = (float*)d_ws;
        dim3 tb(32, 8, 1);
        dim3 tg(PIX / 32, CCH / 32, NCAM);
        transpose_kernel<<<tg, tb, 0, stream>>>(img, imgT);
        gather_lds_kernel<<<NQ / QT, 256, 0, stream>>>(imgT, points, valid, out);
    } else {
        gather_direct_kernel<<<NQ / 256, 256, 0, stream>>>(img, points, valid, out);
    }
}